// Round 1
// baseline (111.551 us; speedup 1.0000x reference)
//
#include <hip/hip_runtime.h>
#include <stdint.h>

#define NUM_LAYERS 24
#define LN_EPS 1e-5f
#define N_ROWS (256 * 8192)
#define NUM_BLOCKS 2048   // 8192 waves x 256 rows/wave, straight-line

typedef __attribute__((ext_vector_type(4)))  uint32_t u32x4;   // MFMA A/B operand
typedef __attribute__((ext_vector_type(16))) float    f32x16;  // 32x32 MFMA acc
typedef __attribute__((ext_vector_type(2)))  float    f32x2;
typedef __attribute__((ext_vector_type(4)))  float    f32x4;
typedef __attribute__((ext_vector_type(2)))  __fp16   h16x2;

// ---- f16 packing helpers ----
__device__ __forceinline__ uint32_t pk_f16_rtz(float lo, float hi) {
    h16x2 v = __builtin_amdgcn_cvt_pkrtz(lo, hi);   // v_cvt_pkrtz_f16_f32
    uint32_t u; __builtin_memcpy(&u, &v, 4);
    return u;
}
__device__ __forceinline__ uint32_t pk_f16_rne(float lo, float hi) {  // setup only
    __fp16 a = (__fp16)lo, b = (__fp16)hi;
    uint16_t ua, ub;
    __builtin_memcpy(&ua, &a, 2); __builtin_memcpy(&ub, &b, 2);
    return (uint32_t)ua | ((uint32_t)ub << 16);
}
__device__ __forceinline__ uint32_t pk_relu_f16(uint32_t d) {  // v_pk_max_f16
    h16x2 v; __builtin_memcpy(&v, &d, 4);
    h16x2 z = {(__fp16)0.0f, (__fp16)0.0f};
    v = __builtin_elementwise_max(v, z);
    uint32_t u; __builtin_memcpy(&u, &v, 4);
    return u;
}

__device__ __forceinline__ u32x4 make_frag(uint32_t d0, uint32_t d1,
                                           uint32_t d2, uint32_t d3) {
    u32x4 f; f.x = d0; f.y = d1; f.z = d2; f.w = d3;
    return f;
}

// ---- inline-asm MFMA blocks (VGPR form, single s_nop guard) ----
// Layer 1, ONE tile: 2 independent MFMAs, C = inline 0 (32 transient acc regs).
__device__ __forceinline__ void mfma_l1(f32x16& d0, f32x16& d1,
                                        const u32x4& a0, const u32x4& a1,
                                        const u32x4& b) {
    asm("s_nop 2\n\t"
        "v_mfma_f32_32x32x16_f16 %0, %2, %4, 0\n\t"
        "v_mfma_f32_32x32x16_f16 %1, %3, %4, 0"
        : "=&v"(d0), "=&v"(d1)
        : "v"(a0), "v"(a1), "v"(b));
}
// Layer 2: two interleaved 4-deep chains, C = inline 0 (b2 added in epilogue).
__device__ __forceinline__ void mfma_l2z(f32x16& c0, f32x16& c1,
                                         const u32x4& w0, const u32x4& w1,
                                         const u32x4& w2, const u32x4& w3,
                                         const u32x4& h00, const u32x4& h01,
                                         const u32x4& h02, const u32x4& h03,
                                         const u32x4& h10, const u32x4& h11,
                                         const u32x4& h12, const u32x4& h13) {
    asm("s_nop 2\n\t"
        "v_mfma_f32_32x32x16_f16 %0, %2, %6, 0\n\t"
        "v_mfma_f32_32x32x16_f16 %1, %2, %10, 0\n\t"
        "v_mfma_f32_32x32x16_f16 %0, %3, %7, %0\n\t"
        "v_mfma_f32_32x32x16_f16 %1, %3, %11, %1\n\t"
        "v_mfma_f32_32x32x16_f16 %0, %4, %8, %0\n\t"
        "v_mfma_f32_32x32x16_f16 %1, %4, %12, %1\n\t"
        "v_mfma_f32_32x32x16_f16 %0, %5, %9, %0\n\t"
        "v_mfma_f32_32x32x16_f16 %1, %5, %13, %1"
        : "=&v"(c0), "=&v"(c1)
        : "v"(w0), "v"(w1), "v"(w2), "v"(w3),
          "v"(h00), "v"(h01), "v"(h02), "v"(h03),
          "v"(h10), "v"(h11), "v"(h12), "v"(h13));
}
__device__ __forceinline__ void mfma_fence2(f32x16& c0, f32x16& c1) {
    asm volatile("s_nop 7\n\ts_nop 7\n\ts_nop 7" : "+v"(c0), "+v"(c1));
}

// canonical hidden index k placed at layer1-output row-position p (sigma) —
// makes C1's C-layout register order equal the layer2 fragment K order.
__device__ __forceinline__ int sigma_k(int p) {
    int hh = (p >> 2) & 1;
    int base = (p & 31) - 4 * hh;            // {0-3,8-11,16-19,24-27}
    int r = (base & 3) + 4 * (base >> 3);    // [0,16)
    return 32 * (p >> 5) + 16 * (r >> 3) + 8 * hh + (r & 7);
}

__global__ __launch_bounds__(256, 4) void router_mfma(
    const float* __restrict__ x,
    const float* __restrict__ ln_w,
    const float* __restrict__ ln_b,
    const float* __restrict__ W1,
    const float* __restrict__ b1,
    const float* __restrict__ W2,
    const float* __restrict__ b2,
    const float* __restrict__ W3,
    const float* __restrict__ b3,
    float* __restrict__ out)
{
    // ---- block-cooperative weight tables in LDS ----
    __shared__ uint32_t s_a1[2 * 64 * 4];   // a1f[mt][lane] 4 dwords
    __shared__ uint32_t s_w2[4 * 64 * 4];   // w2f[kt][lane] 4 dwords
    __shared__ float    s_wb[8 * 64 * 4];   // {w3x,w3y,b2x,b2y} per (r2,lane)
    __shared__ f32x2    s_lnp[4 * NUM_LAYERS];  // {ln_w, ln_b} pairs: 1x b64 gather/q

    const int t = threadIdx.x;

    if (t < 4 * NUM_LAYERS) {               // 96 pairs {w_q[lid], b_q[lid]}
        const int q = t / NUM_LAYERS, lid = t % NUM_LAYERS;
        f32x2 v;
        v.x = ln_w[lid * 4 + q];
        v.y = ln_b[lid * 4 + q];
        s_lnp[t] = v;
    }
    if (t < 128) {
        const int mt = t >> 6, ln = t & 63;
        const int n32l = ln & 31, hl = ln >> 5;
        uint32_t d0 = 0, d1 = 0, d2 = 0;
        if (!hl) {                       // A cols k>=8 are zero
            const int k = sigma_k(mt * 32 + n32l);
            d0 = pk_f16_rne(W1[k * 5 + 0], W1[k * 5 + 1]);
            d1 = pk_f16_rne(W1[k * 5 + 2], W1[k * 5 + 3]);
            d2 = pk_f16_rne(W1[k * 5 + 4], b1[k]);
        }
        uint32_t* p = &s_a1[(mt * 64 + ln) * 4];
        p[0] = d0; p[1] = d1; p[2] = d2; p[3] = 0;
    }
    {
        const int kt = t >> 6, ln = t & 63;
        const int n32l = ln & 31, hl = ln >> 5;
        const float* wp = W2 + n32l * 64 + kt * 16 + hl * 8;
        const float4 lo = *(const float4*)(wp);
        const float4 hi = *(const float4*)(wp + 4);
        uint32_t* p = &s_w2[(kt * 64 + ln) * 4];
        p[0] = pk_f16_rne(lo.x, lo.y);
        p[1] = pk_f16_rne(lo.z, lo.w);
        p[2] = pk_f16_rne(hi.x, hi.y);
        p[3] = pk_f16_rne(hi.z, hi.w);
    }
#pragma unroll
    for (int e = t; e < 512; e += 256) {
        const int r2 = e >> 6, ln = e & 63;
        const int hl = ln >> 5;
        const int n = ((2 * r2) & 3) + 8 * (r2 >> 1) + 4 * hl;
        float* p = &s_wb[e * 4];
        p[0] = W3[n]; p[1] = W3[n + 1];
        p[2] = b2[n]; p[3] = b2[n + 1];
    }
    __syncthreads();

    const int lane = t & 63;
    const int wid  = t >> 6;
    const int h    = lane >> 5;

    // ---- per-wave persistent fragments (24 regs) ----
    u32x4 a1f[2], w2f[4];
#pragma unroll
    for (int mt = 0; mt < 2; ++mt)
        a1f[mt] = *(const u32x4*)&s_a1[(mt * 64 + lane) * 4];
#pragma unroll
    for (int kt = 0; kt < 4; ++kt)
        w2f[kt] = *(const u32x4*)&s_w2[(kt * 64 + lane) * 4];

    const float b3v = b3[0];
    const f32x2 z2 = {0.0f, 0.0f};

    // ---- straight line: this wave owns 256 consecutive rows (4 groups) ----
    const int w = blockIdx.x * 4 + wid;            // 0..8191
    const size_t rowBase = (size_t)w * 256;

    // issue ALL x loads up front (8 independent VMEM ops, latency overlapped).
    // NON-TEMPORAL: x has zero reuse in-kernel; nt avoids allocating in L2/L3,
    // which avoids evicting (and writing back) the dirty lines the harness's
    // 256 MiB poison fill left in the cache hierarchy.
    f32x4 cv[4];
    float cl[4];
#pragma unroll
    for (int g = 0; g < 4; ++g) {
        const float* p = x + (rowBase + 64 * g + lane) * 5;
        cv[g] = __builtin_nontemporal_load((const f32x4*)p);
        cl[g] = __builtin_nontemporal_load(p + 4);
    }

#pragma unroll
    for (int g = 0; g < 4; ++g) {
        const size_t gbase = rowBase + 64 * g;

        // ---- LayerNorm of row (gbase + lane) ----
        int lid = (int)(cl[g] * (float)NUM_LAYERS);
        lid = lid < 0 ? 0 : (lid > NUM_LAYERS - 1 ? NUM_LAYERS - 1 : lid);

        const float m  = (cv[g].x + cv[g].y + cv[g].z + cv[g].w) * 0.25f;
        const float d0 = cv[g].x - m, d1 = cv[g].y - m,
                    d2 = cv[g].z - m, d3 = cv[g].w - m;
        const float var = (d0 * d0 + d1 * d1 + d2 * d2 + d3 * d3) * 0.25f;
        const float r   = __builtin_amdgcn_rsqf(var + LN_EPS);  // raw v_rsq_f32

        const f32x2 p0 = s_lnp[0 * NUM_LAYERS + lid];   // 4x ds_read_b64 gather
        const f32x2 p1 = s_lnp[1 * NUM_LAYERS + lid];
        const f32x2 p2 = s_lnp[2 * NUM_LAYERS + lid];
        const f32x2 p3 = s_lnp[3 * NUM_LAYERS + lid];
        const float xn0 = fmaf(d0, r * p0.x, p0.y);
        const float xn1 = fmaf(d1, r * p1.x, p1.y);
        const float xn2 = fmaf(d2, r * p2.x, p2.y);
        const float xn3 = fmaf(d3, r * p3.x, p3.y);

        // packed normed features (+1.0 slot at q=5 for the b1 fold)
        const uint32_t e0 = pk_f16_rtz(xn0, xn1);
        const uint32_t e1 = pk_f16_rtz(xn2, xn3);
        const uint32_t e2 = pk_f16_rtz(cl[g], 1.0f);
        const uint32_t x0 = __shfl_xor((int)e0, 32, 64);
        const uint32_t x1 = __shfl_xor((int)e1, 32, 64);
        const uint32_t x2 = __shfl_xor((int)e2, 32, 64);

        const u32x4 bf_t0 = make_frag(e0, e1, e2, 0u);   // rows +0..31
        const u32x4 bf_t1 = make_frag(x0, x1, x2, 0u);   // rows +32..63

        // ---- layer 1, tile 0 (32 transient acc regs, repacked immediately) --
        u32x4 h1f0[4], h1f1[4];
        {
            f32x16 c1a, c1b;
            mfma_l1(c1a, c1b, a1f[0], a1f[1], bf_t0);
            mfma_fence2(c1a, c1b);
#pragma unroll
            for (int kt = 0; kt < 4; ++kt) {
                const f32x16& c1 = (kt < 2) ? c1a : c1b;
                const int roff = 8 * (kt & 1);
                uint32_t dw[4];
#pragma unroll
                for (int d = 0; d < 4; ++d)
                    dw[d] = pk_relu_f16(
                        pk_f16_rtz(c1[roff + 2 * d], c1[roff + 2 * d + 1]));
                h1f0[kt] = make_frag(dw[0], dw[1], dw[2], dw[3]);
            }
        }
        // ---- layer 1, tile 1 ----
        {
            f32x16 c1a, c1b;
            mfma_l1(c1a, c1b, a1f[0], a1f[1], bf_t1);
            mfma_fence2(c1a, c1b);
#pragma unroll
            for (int kt = 0; kt < 4; ++kt) {
                const f32x16& c1 = (kt < 2) ? c1a : c1b;
                const int roff = 8 * (kt & 1);
                uint32_t dw[4];
#pragma unroll
                for (int d = 0; d < 4; ++d)
                    dw[d] = pk_relu_f16(
                        pk_f16_rtz(c1[roff + 2 * d], c1[roff + 2 * d + 1]));
                h1f1[kt] = make_frag(dw[0], dw[1], dw[2], dw[3]);
            }
        }

        // ---- layer 2: two interleaved chains, C = inline 0 ----
        f32x16 c2_0, c2_1;
        mfma_l2z(c2_0, c2_1,
                 w2f[0], w2f[1], w2f[2], w2f[3],
                 h1f0[0], h1f0[1], h1f0[2], h1f0[3],
                 h1f1[0], h1f1[1], h1f1[2], h1f1[3]);
        mfma_fence2(c2_0, c2_1);

        // ---- layer 3: +b2, relu, dot W3 (weights streamed from LDS) ----
        f32x2 acc0 = z2, acc1 = z2;
#pragma unroll
        for (int r2 = 0; r2 < 8; ++r2) {
            const float4 wb = *(const float4*)&s_wb[(r2 * 64 + lane) * 4];
            f32x2 v0 = {c2_0[2 * r2] + wb.z, c2_0[2 * r2 + 1] + wb.w};
            f32x2 v1 = {c2_1[2 * r2] + wb.z, c2_1[2 * r2 + 1] + wb.w};
            v0 = __builtin_elementwise_max(v0, z2);
            v1 = __builtin_elementwise_max(v1, z2);
            const f32x2 w3v = {wb.x, wb.y};
            acc0 = v0 * w3v + acc0;
            acc1 = v1 * w3v + acc1;
        }
        float q0 = acc0.x + acc0.y;
        float q1 = acc1.x + acc1.y;
        q0 += __shfl_xor(q0, 32, 64);
        q1 += __shfl_xor(q1, 32, 64);

        // non-temporal store: out is re-poisoned by the harness next iteration;
        // don't allocate it in cache (no dirty-victim write-back traffic).
        __builtin_nontemporal_store((h ? q1 : q0) + b3v, &out[gbase + lane]);
    }
}

extern "C" void kernel_launch(void* const* d_in, const int* in_sizes, int n_in,
                              void* d_out, int out_size, void* d_ws, size_t ws_size,
                              hipStream_t stream) {
    const float* x    = (const float*)d_in[0];
    const float* ln_w = (const float*)d_in[1];
    const float* ln_b = (const float*)d_in[2];
    const float* W1   = (const float*)d_in[3];
    const float* b1   = (const float*)d_in[4];
    const float* W2   = (const float*)d_in[5];
    const float* b2   = (const float*)d_in[6];
    const float* W3   = (const float*)d_in[7];
    const float* b3   = (const float*)d_in[8];
    float* out = (float*)d_out;

    router_mfma<<<NUM_BLOCKS, 256, 0, stream>>>(x, ln_w, ln_b, W1, b1, W2, b2,
                                                W3, b3, out);
}

// Round 2
// 104.688 us; speedup vs baseline: 1.0656x; 1.0656x over previous
//
#include <hip/hip_runtime.h>
#include <stdint.h>

#define NUM_LAYERS 24
#define LN_EPS 1e-5f
#define N_ROWS (256 * 8192)
#define NUM_BLOCKS 1024   // single generation: 4 blocks/CU x 256 CU, all resident
                          // 4096 waves x 512 rows/wave

typedef __attribute__((ext_vector_type(4)))  uint32_t u32x4;   // MFMA A/B operand
typedef __attribute__((ext_vector_type(16))) float    f32x16;  // 32x32 MFMA acc
typedef __attribute__((ext_vector_type(2)))  float    f32x2;
typedef __attribute__((ext_vector_type(4)))  float    f32x4;
typedef __attribute__((ext_vector_type(2)))  __fp16   h16x2;

// ---- f16 packing helpers ----
__device__ __forceinline__ uint32_t pk_f16_rtz(float lo, float hi) {
    h16x2 v = __builtin_amdgcn_cvt_pkrtz(lo, hi);   // v_cvt_pkrtz_f16_f32
    uint32_t u; __builtin_memcpy(&u, &v, 4);
    return u;
}
__device__ __forceinline__ uint32_t pk_f16_rne(float lo, float hi) {  // setup only
    __fp16 a = (__fp16)lo, b = (__fp16)hi;
    uint16_t ua, ub;
    __builtin_memcpy(&ua, &a, 2); __builtin_memcpy(&ub, &b, 2);
    return (uint32_t)ua | ((uint32_t)ub << 16);
}
__device__ __forceinline__ uint32_t pk_relu_f16(uint32_t d) {  // v_pk_max_f16
    h16x2 v; __builtin_memcpy(&v, &d, 4);
    h16x2 z = {(__fp16)0.0f, (__fp16)0.0f};
    v = __builtin_elementwise_max(v, z);
    uint32_t u; __builtin_memcpy(&u, &v, 4);
    return u;
}

__device__ __forceinline__ u32x4 make_frag(uint32_t d0, uint32_t d1,
                                           uint32_t d2, uint32_t d3) {
    u32x4 f; f.x = d0; f.y = d1; f.z = d2; f.w = d3;
    return f;
}

// ---- inline-asm MFMA blocks (VGPR form, single s_nop guard) ----
// Layer 1, ONE tile: 2 independent MFMAs, C = inline 0 (32 transient acc regs).
__device__ __forceinline__ void mfma_l1(f32x16& d0, f32x16& d1,
                                        const u32x4& a0, const u32x4& a1,
                                        const u32x4& b) {
    asm("s_nop 2\n\t"
        "v_mfma_f32_32x32x16_f16 %0, %2, %4, 0\n\t"
        "v_mfma_f32_32x32x16_f16 %1, %3, %4, 0"
        : "=&v"(d0), "=&v"(d1)
        : "v"(a0), "v"(a1), "v"(b));
}
// Layer 2: two interleaved 4-deep chains, C = inline 0 (b2 added in epilogue).
__device__ __forceinline__ void mfma_l2z(f32x16& c0, f32x16& c1,
                                         const u32x4& w0, const u32x4& w1,
                                         const u32x4& w2, const u32x4& w3,
                                         const u32x4& h00, const u32x4& h01,
                                         const u32x4& h02, const u32x4& h03,
                                         const u32x4& h10, const u32x4& h11,
                                         const u32x4& h12, const u32x4& h13) {
    asm("s_nop 2\n\t"
        "v_mfma_f32_32x32x16_f16 %0, %2, %6, 0\n\t"
        "v_mfma_f32_32x32x16_f16 %1, %2, %10, 0\n\t"
        "v_mfma_f32_32x32x16_f16 %0, %3, %7, %0\n\t"
        "v_mfma_f32_32x32x16_f16 %1, %3, %11, %1\n\t"
        "v_mfma_f32_32x32x16_f16 %0, %4, %8, %0\n\t"
        "v_mfma_f32_32x32x16_f16 %1, %4, %12, %1\n\t"
        "v_mfma_f32_32x32x16_f16 %0, %5, %9, %0\n\t"
        "v_mfma_f32_32x32x16_f16 %1, %5, %13, %1"
        : "=&v"(c0), "=&v"(c1)
        : "v"(w0), "v"(w1), "v"(w2), "v"(w3),
          "v"(h00), "v"(h01), "v"(h02), "v"(h03),
          "v"(h10), "v"(h11), "v"(h12), "v"(h13));
}
__device__ __forceinline__ void mfma_fence2(f32x16& c0, f32x16& c1) {
    asm volatile("s_nop 7\n\ts_nop 7\n\ts_nop 7" : "+v"(c0), "+v"(c1));
}

// canonical hidden index k placed at layer1-output row-position p (sigma) —
// makes C1's C-layout register order equal the layer2 fragment K order.
__device__ __forceinline__ int sigma_k(int p) {
    int hh = (p >> 2) & 1;
    int base = (p & 31) - 4 * hh;            // {0-3,8-11,16-19,24-27}
    int r = (base & 3) + 4 * (base >> 3);    // [0,16)
    return 32 * (p >> 5) + 16 * (r >> 3) + 8 * hh + (r & 7);
}

__global__ __launch_bounds__(256, 4) void router_mfma(
    const float* __restrict__ x,
    const float* __restrict__ ln_w,
    const float* __restrict__ ln_b,
    const float* __restrict__ W1,
    const float* __restrict__ b1,
    const float* __restrict__ W2,
    const float* __restrict__ b2,
    const float* __restrict__ W3,
    const float* __restrict__ b3,
    float* __restrict__ out)
{
    // ---- block-cooperative weight tables in LDS ----
    __shared__ uint32_t s_a1[2 * 64 * 4];   // a1f[mt][lane] 4 dwords
    __shared__ uint32_t s_w2[4 * 64 * 4];   // w2f[kt][lane] 4 dwords
    __shared__ float    s_wb[8 * 64 * 4];   // {w3x,w3y,b2x,b2y} per (r2,lane)
    __shared__ f32x2    s_lnp[4 * NUM_LAYERS];  // {ln_w, ln_b} pairs: 1x b64 gather/q

    const int t = threadIdx.x;

    if (t < 4 * NUM_LAYERS) {               // 96 pairs {w_q[lid], b_q[lid]}
        const int q = t / NUM_LAYERS, lid = t % NUM_LAYERS;
        f32x2 v;
        v.x = ln_w[lid * 4 + q];
        v.y = ln_b[lid * 4 + q];
        s_lnp[t] = v;
    }
    if (t < 128) {
        const int mt = t >> 6, ln = t & 63;
        const int n32l = ln & 31, hl = ln >> 5;
        uint32_t d0 = 0, d1 = 0, d2 = 0;
        if (!hl) {                       // A cols k>=8 are zero
            const int k = sigma_k(mt * 32 + n32l);
            d0 = pk_f16_rne(W1[k * 5 + 0], W1[k * 5 + 1]);
            d1 = pk_f16_rne(W1[k * 5 + 2], W1[k * 5 + 3]);
            d2 = pk_f16_rne(W1[k * 5 + 4], b1[k]);
        }
        uint32_t* p = &s_a1[(mt * 64 + ln) * 4];
        p[0] = d0; p[1] = d1; p[2] = d2; p[3] = 0;
    }
    {
        const int kt = t >> 6, ln = t & 63;
        const int n32l = ln & 31, hl = ln >> 5;
        const float* wp = W2 + n32l * 64 + kt * 16 + hl * 8;
        const float4 lo = *(const float4*)(wp);
        const float4 hi = *(const float4*)(wp + 4);
        uint32_t* p = &s_w2[(kt * 64 + ln) * 4];
        p[0] = pk_f16_rne(lo.x, lo.y);
        p[1] = pk_f16_rne(lo.z, lo.w);
        p[2] = pk_f16_rne(hi.x, hi.y);
        p[3] = pk_f16_rne(hi.z, hi.w);
    }
#pragma unroll
    for (int e = t; e < 512; e += 256) {
        const int r2 = e >> 6, ln = e & 63;
        const int hl = ln >> 5;
        const int n = ((2 * r2) & 3) + 8 * (r2 >> 1) + 4 * hl;
        float* p = &s_wb[e * 4];
        p[0] = W3[n]; p[1] = W3[n + 1];
        p[2] = b2[n]; p[3] = b2[n + 1];
    }
    __syncthreads();

    const int lane = t & 63;
    const int wid  = t >> 6;
    const int h    = lane >> 5;

    // ---- per-wave persistent fragments (24 regs) ----
    u32x4 a1f[2], w2f[4];
#pragma unroll
    for (int mt = 0; mt < 2; ++mt)
        a1f[mt] = *(const u32x4*)&s_a1[(mt * 64 + lane) * 4];
#pragma unroll
    for (int kt = 0; kt < 4; ++kt)
        w2f[kt] = *(const u32x4*)&s_w2[(kt * 64 + lane) * 4];

    const float b3v = b3[0];
    const f32x2 z2 = {0.0f, 0.0f};

    // ---- single generation: this wave owns 512 consecutive rows (8 groups),
    //      rolling prefetch distance 4 keeps 4-5 groups' loads in flight for
    //      the wave's whole lifetime (no generation bubble, no MLP drain) ----
    const int w = blockIdx.x * 4 + wid;            // 0..4095
    const size_t rowBase = (size_t)w * 512;

    f32x4 cv[8];
    float  cl[8];
#pragma unroll
    for (int g = 0; g < 4; ++g) {
        const float* p = x + (rowBase + 64 * g + lane) * 5;
        cv[g] = *(const f32x4*)p;
        cl[g] = p[4];
    }

#pragma unroll
    for (int g = 0; g < 8; ++g) {
        // prefetch group g+4 before consuming group g
        if (g < 4) {
            const float* p = x + (rowBase + 64 * (g + 4) + lane) * 5;
            cv[g + 4] = *(const f32x4*)p;
            cl[g + 4] = p[4];
        }

        const size_t gbase = rowBase + 64 * g;

        // ---- LayerNorm of row (gbase + lane) ----
        int lid = (int)(cl[g] * (float)NUM_LAYERS);
        lid = lid < 0 ? 0 : (lid > NUM_LAYERS - 1 ? NUM_LAYERS - 1 : lid);

        const float m  = (cv[g].x + cv[g].y + cv[g].z + cv[g].w) * 0.25f;
        const float d0 = cv[g].x - m, d1 = cv[g].y - m,
                    d2 = cv[g].z - m, d3 = cv[g].w - m;
        const float var = (d0 * d0 + d1 * d1 + d2 * d2 + d3 * d3) * 0.25f;
        const float r   = __builtin_amdgcn_rsqf(var + LN_EPS);  // raw v_rsq_f32

        const f32x2 p0 = s_lnp[0 * NUM_LAYERS + lid];   // 4x ds_read_b64 gather
        const f32x2 p1 = s_lnp[1 * NUM_LAYERS + lid];
        const f32x2 p2 = s_lnp[2 * NUM_LAYERS + lid];
        const f32x2 p3 = s_lnp[3 * NUM_LAYERS + lid];
        const float xn0 = fmaf(d0, r * p0.x, p0.y);
        const float xn1 = fmaf(d1, r * p1.x, p1.y);
        const float xn2 = fmaf(d2, r * p2.x, p2.y);
        const float xn3 = fmaf(d3, r * p3.x, p3.y);

        // packed normed features (+1.0 slot at q=5 for the b1 fold)
        const uint32_t e0 = pk_f16_rtz(xn0, xn1);
        const uint32_t e1 = pk_f16_rtz(xn2, xn3);
        const uint32_t e2 = pk_f16_rtz(cl[g], 1.0f);
        const uint32_t x0 = __shfl_xor((int)e0, 32, 64);
        const uint32_t x1 = __shfl_xor((int)e1, 32, 64);
        const uint32_t x2 = __shfl_xor((int)e2, 32, 64);

        const u32x4 bf_t0 = make_frag(e0, e1, e2, 0u);   // rows +0..31
        const u32x4 bf_t1 = make_frag(x0, x1, x2, 0u);   // rows +32..63

        // ---- layer 1, tile 0 (32 transient acc regs, repacked immediately) --
        u32x4 h1f0[4], h1f1[4];
        {
            f32x16 c1a, c1b;
            mfma_l1(c1a, c1b, a1f[0], a1f[1], bf_t0);
            mfma_fence2(c1a, c1b);
#pragma unroll
            for (int kt = 0; kt < 4; ++kt) {
                const f32x16& c1 = (kt < 2) ? c1a : c1b;
                const int roff = 8 * (kt & 1);
                uint32_t dw[4];
#pragma unroll
                for (int d = 0; d < 4; ++d)
                    dw[d] = pk_relu_f16(
                        pk_f16_rtz(c1[roff + 2 * d], c1[roff + 2 * d + 1]));
                h1f0[kt] = make_frag(dw[0], dw[1], dw[2], dw[3]);
            }
        }
        // ---- layer 1, tile 1 ----
        {
            f32x16 c1a, c1b;
            mfma_l1(c1a, c1b, a1f[0], a1f[1], bf_t1);
            mfma_fence2(c1a, c1b);
#pragma unroll
            for (int kt = 0; kt < 4; ++kt) {
                const f32x16& c1 = (kt < 2) ? c1a : c1b;
                const int roff = 8 * (kt & 1);
                uint32_t dw[4];
#pragma unroll
                for (int d = 0; d < 4; ++d)
                    dw[d] = pk_relu_f16(
                        pk_f16_rtz(c1[roff + 2 * d], c1[roff + 2 * d + 1]));
                h1f1[kt] = make_frag(dw[0], dw[1], dw[2], dw[3]);
            }
        }

        // ---- layer 2: two interleaved chains, C = inline 0 ----
        f32x16 c2_0, c2_1;
        mfma_l2z(c2_0, c2_1,
                 w2f[0], w2f[1], w2f[2], w2f[3],
                 h1f0[0], h1f0[1], h1f0[2], h1f0[3],
                 h1f1[0], h1f1[1], h1f1[2], h1f1[3]);
        mfma_fence2(c2_0, c2_1);

        // ---- layer 3: +b2, relu, dot W3 (weights streamed from LDS) ----
        f32x2 acc0 = z2, acc1 = z2;
#pragma unroll
        for (int r2 = 0; r2 < 8; ++r2) {
            const float4 wb = *(const float4*)&s_wb[(r2 * 64 + lane) * 4];
            f32x2 v0 = {c2_0[2 * r2] + wb.z, c2_0[2 * r2 + 1] + wb.w};
            f32x2 v1 = {c2_1[2 * r2] + wb.z, c2_1[2 * r2 + 1] + wb.w};
            v0 = __builtin_elementwise_max(v0, z2);
            v1 = __builtin_elementwise_max(v1, z2);
            const f32x2 w3v = {wb.x, wb.y};
            acc0 = v0 * w3v + acc0;
            acc1 = v1 * w3v + acc1;
        }
        float q0 = acc0.x + acc0.y;
        float q1 = acc1.x + acc1.y;
        q0 += __shfl_xor(q0, 32, 64);
        q1 += __shfl_xor(q1, 32, 64);

        out[gbase + lane] = (h ? q1 : q0) + b3v;
    }
}

extern "C" void kernel_launch(void* const* d_in, const int* in_sizes, int n_in,
                              void* d_out, int out_size, void* d_ws, size_t ws_size,
                              hipStream_t stream) {
    const float* x    = (const float*)d_in[0];
    const float* ln_w = (const float*)d_in[1];
    const float* ln_b = (const float*)d_in[2];
    const float* W1   = (const float*)d_in[3];
    const float* b1   = (const float*)d_in[4];
    const float* W2   = (const float*)d_in[5];
    const float* b2   = (const float*)d_in[6];
    const float* W3   = (const float*)d_in[7];
    const float* b3   = (const float*)d_in[8];
    float* out = (float*)d_out;

    router_mfma<<<NUM_BLOCKS, 256, 0, stream>>>(x, ln_w, ln_b, W1, b1, W2, b2,
                                                W3, b3, out);
}